// Round 3
// baseline (90.969 us; speedup 1.0000x reference)
//
#include <hip/hip_runtime.h>
#include <hip/hip_bf16.h>

// SE_loss: BCE(se_pred[64,6], class-presence(target[64,512,512] int32)) -> scalar.
//
// Single fused dispatch. 64 blocks (one per batch):
//   phase 1: early-exit presence scan (mask is a monotone OR toward 0x3F; once
//            full, later pixels can't change it -> reads ~16 KB/batch expected,
//            full 1 MB/batch worst case; exact for all inputs).
//   phase 2: publish tagged mask via seq-cst agent-scope atomic store; every
//            block seq-cst-loads all 64 slots; whichever block(s) see all 64
//            valid (at least the last one in the seq-cst total order must)
//            compute the BCE epilogue. Duplicate writers produce bitwise-
//            identical values -> benign. No zeroed counter, no spin, no
//            dispatch-order assumption.

#define NCLASS 6
#define NBATCH 64
#define PER_BATCH (512 * 512)       // int32 elements per batch image
#define PK_THREADS 1024             // 16 waves
#define TAG     0x5E000000u         // high-entropy "slot published" tag
#define TAGMASK 0xFFFFFF80u         // mask fits in low 7 bits

__global__ __launch_bounds__(PK_THREADS) void fused_kernel(
    const float* __restrict__ se_pred, const int* __restrict__ target,
    unsigned* __restrict__ masks, float* __restrict__ out) {
    const int batch = blockIdx.x;
    const int4* __restrict__ p =
        (const int4*)(target + (size_t)batch * PER_BATCH);

    // ---- phase 1: presence scan with early exit ----
    __shared__ unsigned sm;
    if (threadIdx.x == 0) sm = 0u;
    __syncthreads();

    const int NV = PER_BATCH / 4;   // 65536 int4 vectors per batch
    for (int base = 0; base < NV; base += PK_THREADS) {   // up to 64 iters
        int4 v = p[base + (int)threadIdx.x];
        unsigned m = (1u << v.x) | (1u << v.y) | (1u << v.z) | (1u << v.w);
#pragma unroll
        for (int off = 32; off > 0; off >>= 1)
            m |= (unsigned)__shfl_down((int)m, off, 64);
        if ((threadIdx.x & 63) == 0) atomicOr(&sm, m);
        __syncthreads();
        if (sm == 0x3Fu) break;     // uniform: sm identical across the block
        __syncthreads();
    }
    __syncthreads();

    // ---- phase 2: publish + check ----
    if (threadIdx.x == 0)
        __hip_atomic_store(&masks[batch], TAG | sm,
                           __ATOMIC_SEQ_CST, __HIP_MEMORY_SCOPE_AGENT);
    __syncthreads();

    // speculative prefetch of se_pred (hides latency behind the slot loads)
    float pv = 0.5f;
    if (threadIdx.x < NBATCH * NCLASS) pv = se_pred[threadIdx.x];

    __shared__ unsigned slots[NBATCH];
    __shared__ int nvalid;
    if (threadIdx.x == 0) nvalid = 0;
    __syncthreads();
    if (threadIdx.x < NBATCH) {
        unsigned v = __hip_atomic_load(&masks[threadIdx.x],
                                       __ATOMIC_SEQ_CST, __HIP_MEMORY_SCOPE_AGENT);
        slots[threadIdx.x] = v;
        if ((v & TAGMASK) == TAG) atomicAdd(&nvalid, 1);
    }
    __syncthreads();
    if (nvalid != NBATCH) return;   // not last; someone later will see all-valid

    // ---- BCE epilogue (any all-valid block; identical result bitwise) ----
    float term = 0.0f;
    if (threadIdx.x < NBATCH * NCLASS) {
        const int b = (int)threadIdx.x / NCLASS;
        const int c = (int)threadIdx.x % NCLASS;
        const float t = ((slots[b] >> c) & 1u) ? 1.0f : 0.0f;
        const float lp  = fmaxf(logf(pv), -100.0f);     // torch log clamp
        const float l1p = fmaxf(log1pf(-pv), -100.0f);
        term = -(t * lp + (1.0f - t) * l1p);
    }
#pragma unroll
    for (int off = 32; off > 0; off >>= 1)
        term += __shfl_down(term, off, 64);

    __shared__ float partial[PK_THREADS / 64];
    if ((threadIdx.x & 63) == 0) partial[threadIdx.x >> 6] = term;
    __syncthreads();
    if (threadIdx.x == 0) {
        float s = 0.0f;
#pragma unroll
        for (int w = 0; w < PK_THREADS / 64; ++w) s += partial[w];
        out[0] = s * (1.0f / (NBATCH * NCLASS));
    }
}

extern "C" void kernel_launch(void* const* d_in, const int* in_sizes, int n_in,
                              void* d_out, int out_size, void* d_ws, size_t ws_size,
                              hipStream_t stream) {
    const float* se_pred = (const float*)d_in[0];   // [64,6] fp32
    const int*   target  = (const int*)d_in[1];     // [64,512,512] int32
    float*       out     = (float*)d_out;           // scalar fp32
    unsigned*    masks   = (unsigned*)d_ws;         // 64 tagged presence slots

    fused_kernel<<<NBATCH, PK_THREADS, 0, stream>>>(se_pred, target, masks, out);
}